// Round 6
// baseline (344.335 us; speedup 1.0000x reference)
//
#include <hip/hip_runtime.h>
#include <math.h>

typedef unsigned int  u32;
typedef unsigned short u16;

// Problem constants (match reference)
#define NN    50000
#define NE    800000
#define ET    (NE + NN)     // edges + self loops = 850000
#define IND   128
#define HIDD  128
#define NH    8
#define OD    64
#define SLOPE 0.2f
#define NBLK  196           // ceil(NN/256) scan blocks

// bf16 round-to-nearest-even, returns low 16 bits
__device__ __forceinline__ u32 bf16rne(float f) {
    u32 u = __float_as_uint(f);
    return (u + 0x7fffu + ((u >> 16) & 1u)) >> 16;
}

// leaky_relu(s) == max(s, SLOPE*s) for 0 < SLOPE < 1
#define LR(s) fmaxf((s), SLOPE * (s))

// ---------------------------------------------------------------------------
// CSR build: degree histogram -> 3-stage hierarchical exclusive scan ->
// scatter (sorted_src only). deg lives in cursor[]; scanC overwrites in
// place with start offsets. After scatter, cursor[i] == end offset.
// ---------------------------------------------------------------------------
__global__ __launch_bounds__(256) void k_deg(
    const int* __restrict__ ei, int* __restrict__ deg)
{
    const int e = blockIdx.x * 256 + threadIdx.x;
    if (e >= ET) return;
    const int dst = (e < NE) ? ei[NE + e] : (e - NE);
    atomicAdd(&deg[dst], 1);
}

__global__ __launch_bounds__(256) void k_scanA(
    const int* __restrict__ deg, int* __restrict__ partial)
{
    __shared__ int s[256];
    const int t = threadIdx.x;
    const int idx = blockIdx.x * 256 + t;
    s[t] = (idx < NN) ? deg[idx] : 0;
    __syncthreads();
    for (int off = 128; off > 0; off >>= 1) {
        if (t < off) s[t] += s[t + off];
        __syncthreads();
    }
    if (t == 0) partial[blockIdx.x] = s[0];
}

__global__ __launch_bounds__(256) void k_scanB(int* __restrict__ partial)
{
    __shared__ int s[256];
    const int t = threadIdx.x;
    int v = (t < NBLK) ? partial[t] : 0;
    s[t] = v;
    __syncthreads();
    for (int off = 1; off < 256; off <<= 1) {
        int u = (t >= off) ? s[t - off] : 0;
        __syncthreads();
        s[t] += u;
        __syncthreads();
    }
    if (t < NBLK) partial[t] = (t == 0) ? 0 : s[t - 1];   // exclusive
}

__global__ __launch_bounds__(256) void k_scanC(
    int* __restrict__ degcur,           // in: deg, out: start offsets
    const int* __restrict__ partial, int* __restrict__ rowptr)
{
    __shared__ int s[256];
    const int t = threadIdx.x;
    const int idx = blockIdx.x * 256 + t;
    const int d = (idx < NN) ? degcur[idx] : 0;
    s[t] = d;
    __syncthreads();
    for (int off = 1; off < 256; off <<= 1) {
        int u = (t >= off) ? s[t - off] : 0;
        __syncthreads();
        s[t] += u;
        __syncthreads();
    }
    if (idx < NN) {
        const int excl = ((t == 0) ? 0 : s[t - 1]) + partial[blockIdx.x];
        rowptr[idx] = excl;
        degcur[idx] = excl;             // cursor init
    }
}

__global__ __launch_bounds__(256) void k_scatter(
    const int* __restrict__ ei, int* __restrict__ cursor,
    int* __restrict__ sorted_src)
{
    const int e = blockIdx.x * 256 + threadIdx.x;
    if (e >= ET) return;
    int src, dst;
    if (e < NE) { src = ei[e]; dst = ei[NE + e]; }
    else        { src = dst = e - NE; }
    const int pos = atomicAdd(&cursor[dst], 1);
    sorted_src[pos] = src;
}

// ---------------------------------------------------------------------------
// Register-tiled fp32 GEMMs (64x64 C tile, K=128 staged, XOR-swizzled x tile).
// ---------------------------------------------------------------------------
#define XSW(r, kf) ((r) * 128 + ((kf) ^ (4 * ((r) & 7))))

__device__ __forceinline__ void fma4(float* acc, float a, float4 b) {
    acc[0] += a * b.x; acc[1] += a * b.y; acc[2] += a * b.z; acc[3] += a * b.w;
}

// GEMM1: h1 = x @ W1 (50000x128 @ 128x128), grid (782, 2). Writes h1 as
// packed bf16x2 (gather payload); alphas computed from fp32 accumulators.
__global__ __launch_bounds__(256) void k_gemm1(
    const float* __restrict__ x, const float* __restrict__ W1,
    const float* __restrict__ a_s, const float* __restrict__ a_d,
    u32* __restrict__ h1b, float* __restrict__ as1, float* __restrict__ ad1)
{
    __shared__ float xs[64 * 128];   // 32 KB (swizzled)
    __shared__ float Wl[128 * 64];   // 32 KB
    const int tid = threadIdx.x;
    const int row0 = blockIdx.x * 64;
    const int j0 = blockIdx.y * 64;

    {   // stage W block: 128 k x 64 j
        const int f4c = tid & 15, kk = tid >> 4;
        for (int p = 0; p < 8; ++p) {
            const int k = kk + p * 16;
            *(float4*)(Wl + k * 64 + 4 * f4c) =
                *(const float4*)(W1 + k * IND + j0 + 4 * f4c);
        }
    }
    {   // stage x block: 64 rows x 128 k (swizzled)
        const int f4c = tid & 31, r = tid >> 5;
        for (int p = 0; p < 8; ++p) {
            const int rr = r + p * 8;
            const int row = row0 + rr;
            float4 v = make_float4(0.f, 0.f, 0.f, 0.f);
            if (row < NN) v = *(const float4*)(x + (size_t)row * IND + 4 * f4c);
            *(float4*)(xs + XSW(rr, 4 * f4c)) = v;
        }
    }
    __syncthreads();

    const int tc = tid & 15, tr = tid >> 4;
    float acc[4][4] = {};
    for (int k = 0; k < 128; k += 4) {
        const float4 B0 = *(const float4*)(Wl + (k + 0) * 64 + 4 * tc);
        const float4 B1 = *(const float4*)(Wl + (k + 1) * 64 + 4 * tc);
        const float4 B2 = *(const float4*)(Wl + (k + 2) * 64 + 4 * tc);
        const float4 B3 = *(const float4*)(Wl + (k + 3) * 64 + 4 * tc);
#pragma unroll
        for (int r = 0; r < 4; ++r) {
            const float4 A = *(const float4*)(xs + XSW(4 * tr + r, k));
            fma4(acc[r], A.x, B0); fma4(acc[r], A.y, B1);
            fma4(acc[r], A.z, B2); fma4(acc[r], A.w, B3);
        }
    }

    const float4 asv = *(const float4*)(a_s + j0 + 4 * tc);
    const float4 adv = *(const float4*)(a_d + j0 + 4 * tc);
#pragma unroll
    for (int r = 0; r < 4; ++r) {
        const int row = row0 + 4 * tr + r;
        if (row < NN) {   // guard uniform within shfl groups (varies by tr only)
            const u32 p01 = bf16rne(acc[r][0]) | (bf16rne(acc[r][1]) << 16);
            const u32 p23 = bf16rne(acc[r][2]) | (bf16rne(acc[r][3]) << 16);
            *(uint2*)(h1b + row * 64 + ((j0 + 4 * tc) >> 1)) = make_uint2(p01, p23);
            float ps = acc[r][0] * asv.x + acc[r][1] * asv.y +
                       acc[r][2] * asv.z + acc[r][3] * asv.w;
            float pd = acc[r][0] * adv.x + acc[r][1] * adv.y +
                       acc[r][2] * adv.z + acc[r][3] * adv.w;
            ps += __shfl_xor(ps, 1); ps += __shfl_xor(ps, 2);
            pd += __shfl_xor(pd, 1); pd += __shfl_xor(pd, 2);
            if ((tc & 3) == 0) {
                const int head = blockIdx.y * 4 + (tc >> 2);
                as1[row * NH + head] = ps;
                ad1[row * NH + head] = pd;
            }
        }
    }
}

// GEMM2: h2 = act2 @ W2 (50000x128 @ 128x64), grid (782, 1). Writes h2 as
// bf16 (ushort); fused single-head alpha2 epilogue from fp32 accumulators.
__global__ __launch_bounds__(256) void k_gemm2(
    const float* __restrict__ act2, const float* __restrict__ W2,
    const float* __restrict__ a_s2, const float* __restrict__ a_d2,
    u16* __restrict__ h2s, float* __restrict__ as2, float* __restrict__ ad2)
{
    __shared__ float xs[64 * 128];   // 32 KB (swizzled)
    __shared__ float Wl[128 * 64];   // 32 KB
    const int tid = threadIdx.x;
    const int row0 = blockIdx.x * 64;

    {
        const int f4c = tid & 15, kk = tid >> 4;
        for (int p = 0; p < 8; ++p) {
            const int k = kk + p * 16;
            *(float4*)(Wl + k * 64 + 4 * f4c) =
                *(const float4*)(W2 + k * OD + 4 * f4c);
        }
    }
    {
        const int f4c = tid & 31, r = tid >> 5;
        for (int p = 0; p < 8; ++p) {
            const int rr = r + p * 8;
            const int row = row0 + rr;
            float4 v = make_float4(0.f, 0.f, 0.f, 0.f);
            if (row < NN) v = *(const float4*)(act2 + (size_t)row * HIDD + 4 * f4c);
            *(float4*)(xs + XSW(rr, 4 * f4c)) = v;
        }
    }
    __syncthreads();

    const int tc = tid & 15, tr = tid >> 4;
    float acc[4][4] = {};
    for (int k = 0; k < 128; k += 4) {
        const float4 B0 = *(const float4*)(Wl + (k + 0) * 64 + 4 * tc);
        const float4 B1 = *(const float4*)(Wl + (k + 1) * 64 + 4 * tc);
        const float4 B2 = *(const float4*)(Wl + (k + 2) * 64 + 4 * tc);
        const float4 B3 = *(const float4*)(Wl + (k + 3) * 64 + 4 * tc);
#pragma unroll
        for (int r = 0; r < 4; ++r) {
            const float4 A = *(const float4*)(xs + XSW(4 * tr + r, k));
            fma4(acc[r], A.x, B0); fma4(acc[r], A.y, B1);
            fma4(acc[r], A.z, B2); fma4(acc[r], A.w, B3);
        }
    }

    const float4 asv = *(const float4*)(a_s2 + 4 * tc);
    const float4 adv = *(const float4*)(a_d2 + 4 * tc);
#pragma unroll
    for (int r = 0; r < 4; ++r) {
        const int row = row0 + 4 * tr + r;
        if (row < NN) {
            ushort4 pk;
            pk.x = (u16)bf16rne(acc[r][0]); pk.y = (u16)bf16rne(acc[r][1]);
            pk.z = (u16)bf16rne(acc[r][2]); pk.w = (u16)bf16rne(acc[r][3]);
            *(ushort4*)(h2s + row * 64 + 4 * tc) = pk;
            float ps = acc[r][0] * asv.x + acc[r][1] * asv.y +
                       acc[r][2] * asv.z + acc[r][3] * asv.w;
            float pd = acc[r][0] * adv.x + acc[r][1] * adv.y +
                       acc[r][2] * adv.z + acc[r][3] * adv.w;
            ps += __shfl_xor(ps, 1); ps += __shfl_xor(ps, 2);
            ps += __shfl_xor(ps, 4); ps += __shfl_xor(ps, 8);
            pd += __shfl_xor(pd, 1); pd += __shfl_xor(pd, 2);
            pd += __shfl_xor(pd, 4); pd += __shfl_xor(pd, 8);
            if (tc == 0) { as2[row] = ps; ad2[row] = pd; }
        }
    }
}

// ---------------------------------------------------------------------------
// Aggregation layer 1, CSR gather: one node per wave, lane covers channels
// 2*lane, 2*lane+1 (head = lane>>3). Lane-parallel weight dedup: per 8-edge
// chunk, lane l computes w for (edge kc+(l&7), head l>>3) -> one exp + one
// as1 gather per lane per 8 edges; aggregation shuffles (src,w) from lane
// (lane&56)+j. Fuses normalize (/den) + ELU.
// ---------------------------------------------------------------------------
__global__ __launch_bounds__(256) void k_agg1(
    const int* __restrict__ rowptr, const int* __restrict__ rowend,
    const int* __restrict__ sorted_src,
    const u32* __restrict__ h1b, const float* __restrict__ as1,
    const float* __restrict__ ad1,
    float* __restrict__ act2)
{
    const int node = blockIdx.x * 4 + (threadIdx.x >> 6);
    const int lane = threadIdx.x & 63;
    const int head = lane >> 3;
    const int esub = lane & 7;
    const int base = lane & 56;         // first lane of my head group
    const float adh = ad1[node * NH + head];
    const int k0 = rowptr[node], k1 = rowend[node];
    float acc0 = 0.f, acc1 = 0.f, den = 0.f;
    int kc = k0;
    const int nfull = (k1 - k0) >> 3;
    for (int c = 0; c < nfull; ++c, kc += 8) {
        const int   src_l = sorted_src[kc + esub];
        const float a_l   = as1[src_l * NH + head];
        const float w_l   = __expf(LR(a_l + adh));
#pragma unroll
        for (int j = 0; j < 8; ++j) {
            const int   sj = __shfl(src_l, base + j);
            const float wj = __shfl(w_l,  base + j);
            const u32 u = h1b[sj * 64 + lane];
            acc0 += wj * __uint_as_float(u << 16);
            acc1 += wj * __uint_as_float(u & 0xffff0000u);
            den  += wj;
        }
    }
    for (int k = kc; k < k1; ++k) {     // remainder (<8 edges), scalar path
        const int src = sorted_src[k];
        const float w = __expf(LR(as1[src * NH + head] + adh));
        const u32 u = h1b[src * 64 + lane];
        acc0 += w * __uint_as_float(u << 16);
        acc1 += w * __uint_as_float(u & 0xffff0000u);
        den += w;
    }
    const float inv = 1.f / den;                    // self-loop => den > 0
    float v0 = acc0 * inv, v1 = acc1 * inv;
    v0 = v0 > 0.f ? v0 : expm1f(v0);                // ELU
    v1 = v1 > 0.f ? v1 : expm1f(v1);
    *(float2*)(act2 + node * 128 + 2 * lane) = make_float2(v0, v1);
}

// ---------------------------------------------------------------------------
// Aggregation layer 2 + log_softmax: one node per wave, lane = channel (64).
// Lane-parallel weight dedup per 16-edge chunk (exp 4x/edge instead of 64x),
// shuffle (src,w) from lane j. Fuses normalize + log_softmax -> output.
// ---------------------------------------------------------------------------
__global__ __launch_bounds__(256) void k_agg2(
    const int* __restrict__ rowptr, const int* __restrict__ rowend,
    const int* __restrict__ sorted_src,
    const u16* __restrict__ h2s, const float* __restrict__ as2,
    const float* __restrict__ ad2,
    float* __restrict__ out)
{
    const int node = blockIdx.x * 4 + (threadIdx.x >> 6);
    const int lane = threadIdx.x & 63;
    const float adv = ad2[node];
    const int k0 = rowptr[node], k1 = rowend[node];
    float acc = 0.f, den = 0.f;
    int kc = k0;
    const int nfull = (k1 - k0) >> 4;
    for (int c = 0; c < nfull; ++c, kc += 16) {
        const int   src_l = sorted_src[kc + (lane & 15)];
        const float w_l   = __expf(LR(as2[src_l] + adv));
#pragma unroll
        for (int j = 0; j < 16; ++j) {
            const int   sj = __shfl(src_l, j);
            const float wj = __shfl(w_l,  j);
            acc += wj * __uint_as_float((u32)h2s[sj * 64 + lane] << 16);
            den += wj;
        }
    }
    for (int k = kc; k < k1; ++k) {     // remainder (<16 edges), scalar path
        const int src = sorted_src[k];
        const float w = __expf(LR(as2[src] + adv));
        acc += w * __uint_as_float((u32)h2s[src * 64 + lane] << 16);
        den += w;
    }
    const float v = acc / den;
    float m = v;
    for (int kk = 1; kk < 64; kk <<= 1) m = fmaxf(m, __shfl_xor(m, kk));
    float se = __expf(v - m);
    for (int kk = 1; kk < 64; kk <<= 1) se += __shfl_xor(se, kk);
    out[node * 64 + lane] = v - m - logf(se);
}

// ---------------------------------------------------------------------------
// Workspace (~46 MB, 4-byte units):
//   h1b    [64N] u32 (bf16x2) -> after agg1, reused as h2s [64N] u16
//   as1    [8N]  f32 -> reused as as2 [N]
//   ad1    [8N]  f32 -> reused as ad2 [N]
//   act2   [128N] f32
//   rowptr [N], cursor [N] (deg -> start cursor -> rowend)
//   sorted_src [ET], partial [256]
// ---------------------------------------------------------------------------
extern "C" void kernel_launch(void* const* d_in, const int* in_sizes, int n_in,
                              void* d_out, int out_size, void* d_ws, size_t ws_size,
                              hipStream_t stream)
{
    (void)in_sizes; (void)n_in; (void)out_size; (void)ws_size;
    const float* x    = (const float*)d_in[0];
    const int*   ei   = (const int*)d_in[1];
    const float* W1   = (const float*)d_in[2];
    const float* as1w = (const float*)d_in[3];
    const float* ad1w = (const float*)d_in[4];
    const float* W2   = (const float*)d_in[6];
    const float* as2w = (const float*)d_in[7];
    const float* ad2w = (const float*)d_in[8];
    float* out = (float*)d_out;

    float* ws = (float*)d_ws;
    u32*   h1b  = (u32*)ws;                          // 64N
    float* as1  = ws + (size_t)64 * NN;              // 8N
    float* ad1  = ws + (size_t)72 * NN;              // 8N
    float* act2 = ws + (size_t)80 * NN;              // 128N
    int*   rowptr = (int*)(ws + (size_t)208 * NN);   // N
    int*   cursor = rowptr + NN;                     // N
    int*   sorted_src = cursor + NN;                 // ET
    int*   partial = sorted_src + ET;                // 256
    u16*   h2s = (u16*)h1b;                          // alias (h1b dead after agg1)
    float* as2 = as1;
    float* ad2 = ad1;

    hipMemsetAsync(cursor, 0, NN * sizeof(int), stream);

    const int EB = (ET + 255) / 256;
    k_deg  <<<EB, 256, 0, stream>>>(ei, cursor);
    k_scanA<<<NBLK, 256, 0, stream>>>(cursor, partial);
    k_scanB<<<1, 256, 0, stream>>>(partial);
    k_scanC<<<NBLK, 256, 0, stream>>>(cursor, partial, rowptr);
    k_scatter<<<EB, 256, 0, stream>>>(ei, cursor, sorted_src);

    k_gemm1<<<dim3(782, 2), 256, 0, stream>>>(x, W1, as1w, ad1w, h1b, as1, ad1);
    k_agg1 <<<NN / 4, 256, 0, stream>>>(rowptr, cursor, sorted_src, h1b, as1, ad1, act2);
    k_gemm2<<<dim3(782, 1), 256, 0, stream>>>(act2, W2, as2w, ad2w, h2s, as2, ad2);
    k_agg2 <<<NN / 4, 256, 0, stream>>>(rowptr, cursor, sorted_src, h2s, as2, ad2, out);
}

// Round 7
// 343.907 us; speedup vs baseline: 1.0012x; 1.0012x over previous
//
#include <hip/hip_runtime.h>
#include <math.h>

typedef unsigned int  u32;
typedef unsigned short u16;

// Problem constants (match reference)
#define NN    50000
#define NE    800000
#define ET    (NE + NN)     // edges + self loops = 850000
#define IND   128
#define HIDD  128
#define NH    8
#define OD    64
#define SLOPE 0.2f
#define NBLK  196           // ceil(NN/256) scan blocks

// bf16 round-to-nearest-even, returns low 16 bits
__device__ __forceinline__ u32 bf16rne(float f) {
    u32 u = __float_as_uint(f);
    return (u + 0x7fffu + ((u >> 16) & 1u)) >> 16;
}

// leaky_relu(s) == max(s, SLOPE*s) for 0 < SLOPE < 1
#define LR(s) fmaxf((s), SLOPE * (s))

// ---------------------------------------------------------------------------
// CSR build: degree histogram -> 3-stage hierarchical exclusive scan ->
// scatter (sorted_src only, nontemporal). deg lives in cursor[]; scanC
// overwrites in place with start offsets. After scatter, cursor[i] == end.
// ---------------------------------------------------------------------------
__global__ __launch_bounds__(256) void k_deg(
    const int* __restrict__ ei, int* __restrict__ deg)
{
    const int e = blockIdx.x * 256 + threadIdx.x;
    if (e >= ET) return;
    const int dst = (e < NE) ? ei[NE + e] : (e - NE);
    atomicAdd(&deg[dst], 1);
}

__global__ __launch_bounds__(256) void k_scanA(
    const int* __restrict__ deg, int* __restrict__ partial)
{
    __shared__ int s[256];
    const int t = threadIdx.x;
    const int idx = blockIdx.x * 256 + t;
    s[t] = (idx < NN) ? deg[idx] : 0;
    __syncthreads();
    for (int off = 128; off > 0; off >>= 1) {
        if (t < off) s[t] += s[t + off];
        __syncthreads();
    }
    if (t == 0) partial[blockIdx.x] = s[0];
}

__global__ __launch_bounds__(256) void k_scanB(int* __restrict__ partial)
{
    __shared__ int s[256];
    const int t = threadIdx.x;
    int v = (t < NBLK) ? partial[t] : 0;
    s[t] = v;
    __syncthreads();
    for (int off = 1; off < 256; off <<= 1) {
        int u = (t >= off) ? s[t - off] : 0;
        __syncthreads();
        s[t] += u;
        __syncthreads();
    }
    if (t < NBLK) partial[t] = (t == 0) ? 0 : s[t - 1];   // exclusive
}

__global__ __launch_bounds__(256) void k_scanC(
    int* __restrict__ degcur,           // in: deg, out: start offsets
    const int* __restrict__ partial, int* __restrict__ rowptr)
{
    __shared__ int s[256];
    const int t = threadIdx.x;
    const int idx = blockIdx.x * 256 + t;
    const int d = (idx < NN) ? degcur[idx] : 0;
    s[t] = d;
    __syncthreads();
    for (int off = 1; off < 256; off <<= 1) {
        int u = (t >= off) ? s[t - off] : 0;
        __syncthreads();
        s[t] += u;
        __syncthreads();
    }
    if (idx < NN) {
        const int excl = ((t == 0) ? 0 : s[t - 1]) + partial[blockIdx.x];
        rowptr[idx] = excl;
        degcur[idx] = excl;             // cursor init
    }
}

__global__ __launch_bounds__(256) void k_scatter(
    const int* __restrict__ ei, int* __restrict__ cursor,
    int* __restrict__ sorted_src)
{
    const int e = blockIdx.x * 256 + threadIdx.x;
    if (e >= ET) return;
    int src, dst;
    if (e < NE) { src = ei[e]; dst = ei[NE + e]; }
    else        { src = dst = e - NE; }
    const int pos = atomicAdd(&cursor[dst], 1);
    __builtin_nontemporal_store(src, &sorted_src[pos]);
}

// ---------------------------------------------------------------------------
// Register-tiled fp32 GEMMs (64x64 C tile, K=128 staged, XOR-swizzled x tile).
// ---------------------------------------------------------------------------
#define XSW(r, kf) ((r) * 128 + ((kf) ^ (4 * ((r) & 7))))

__device__ __forceinline__ void fma4(float* acc, float a, float4 b) {
    acc[0] += a * b.x; acc[1] += a * b.y; acc[2] += a * b.z; acc[3] += a * b.w;
}

// GEMM1: h1 = x @ W1 (50000x128 @ 128x128), grid (782, 2). Writes h1 as
// packed bf16x2 (gather payload); alphas computed from fp32 accumulators.
__global__ __launch_bounds__(256) void k_gemm1(
    const float* __restrict__ x, const float* __restrict__ W1,
    const float* __restrict__ a_s, const float* __restrict__ a_d,
    u32* __restrict__ h1b, float* __restrict__ as1, float* __restrict__ ad1)
{
    __shared__ float xs[64 * 128];   // 32 KB (swizzled)
    __shared__ float Wl[128 * 64];   // 32 KB
    const int tid = threadIdx.x;
    const int row0 = blockIdx.x * 64;
    const int j0 = blockIdx.y * 64;

    {   // stage W block: 128 k x 64 j
        const int f4c = tid & 15, kk = tid >> 4;
        for (int p = 0; p < 8; ++p) {
            const int k = kk + p * 16;
            *(float4*)(Wl + k * 64 + 4 * f4c) =
                *(const float4*)(W1 + k * IND + j0 + 4 * f4c);
        }
    }
    {   // stage x block: 64 rows x 128 k (swizzled)
        const int f4c = tid & 31, r = tid >> 5;
        for (int p = 0; p < 8; ++p) {
            const int rr = r + p * 8;
            const int row = row0 + rr;
            float4 v = make_float4(0.f, 0.f, 0.f, 0.f);
            if (row < NN) v = *(const float4*)(x + (size_t)row * IND + 4 * f4c);
            *(float4*)(xs + XSW(rr, 4 * f4c)) = v;
        }
    }
    __syncthreads();

    const int tc = tid & 15, tr = tid >> 4;
    float acc[4][4] = {};
    for (int k = 0; k < 128; k += 4) {
        const float4 B0 = *(const float4*)(Wl + (k + 0) * 64 + 4 * tc);
        const float4 B1 = *(const float4*)(Wl + (k + 1) * 64 + 4 * tc);
        const float4 B2 = *(const float4*)(Wl + (k + 2) * 64 + 4 * tc);
        const float4 B3 = *(const float4*)(Wl + (k + 3) * 64 + 4 * tc);
#pragma unroll
        for (int r = 0; r < 4; ++r) {
            const float4 A = *(const float4*)(xs + XSW(4 * tr + r, k));
            fma4(acc[r], A.x, B0); fma4(acc[r], A.y, B1);
            fma4(acc[r], A.z, B2); fma4(acc[r], A.w, B3);
        }
    }

    const float4 asv = *(const float4*)(a_s + j0 + 4 * tc);
    const float4 adv = *(const float4*)(a_d + j0 + 4 * tc);
#pragma unroll
    for (int r = 0; r < 4; ++r) {
        const int row = row0 + 4 * tr + r;
        if (row < NN) {   // guard uniform within shfl groups (varies by tr only)
            const u32 p01 = bf16rne(acc[r][0]) | (bf16rne(acc[r][1]) << 16);
            const u32 p23 = bf16rne(acc[r][2]) | (bf16rne(acc[r][3]) << 16);
            *(uint2*)(h1b + row * 64 + ((j0 + 4 * tc) >> 1)) = make_uint2(p01, p23);
            float ps = acc[r][0] * asv.x + acc[r][1] * asv.y +
                       acc[r][2] * asv.z + acc[r][3] * asv.w;
            float pd = acc[r][0] * adv.x + acc[r][1] * adv.y +
                       acc[r][2] * adv.z + acc[r][3] * adv.w;
            ps += __shfl_xor(ps, 1); ps += __shfl_xor(ps, 2);
            pd += __shfl_xor(pd, 1); pd += __shfl_xor(pd, 2);
            if ((tc & 3) == 0) {
                const int head = blockIdx.y * 4 + (tc >> 2);
                as1[row * NH + head] = ps;
                ad1[row * NH + head] = pd;
            }
        }
    }
}

// GEMM2: h2 = act2 @ W2 (50000x128 @ 128x64), grid (782, 1). Writes h2 as
// bf16 (ushort); fused single-head alpha2 epilogue from fp32 accumulators.
__global__ __launch_bounds__(256) void k_gemm2(
    const float* __restrict__ act2, const float* __restrict__ W2,
    const float* __restrict__ a_s2, const float* __restrict__ a_d2,
    u16* __restrict__ h2s, float* __restrict__ as2, float* __restrict__ ad2)
{
    __shared__ float xs[64 * 128];   // 32 KB (swizzled)
    __shared__ float Wl[128 * 64];   // 32 KB
    const int tid = threadIdx.x;
    const int row0 = blockIdx.x * 64;

    {
        const int f4c = tid & 15, kk = tid >> 4;
        for (int p = 0; p < 8; ++p) {
            const int k = kk + p * 16;
            *(float4*)(Wl + k * 64 + 4 * f4c) =
                *(const float4*)(W2 + k * OD + 4 * f4c);
        }
    }
    {
        const int f4c = tid & 31, r = tid >> 5;
        for (int p = 0; p < 8; ++p) {
            const int rr = r + p * 8;
            const int row = row0 + rr;
            float4 v = make_float4(0.f, 0.f, 0.f, 0.f);
            if (row < NN) v = *(const float4*)(act2 + (size_t)row * HIDD + 4 * f4c);
            *(float4*)(xs + XSW(rr, 4 * f4c)) = v;
        }
    }
    __syncthreads();

    const int tc = tid & 15, tr = tid >> 4;
    float acc[4][4] = {};
    for (int k = 0; k < 128; k += 4) {
        const float4 B0 = *(const float4*)(Wl + (k + 0) * 64 + 4 * tc);
        const float4 B1 = *(const float4*)(Wl + (k + 1) * 64 + 4 * tc);
        const float4 B2 = *(const float4*)(Wl + (k + 2) * 64 + 4 * tc);
        const float4 B3 = *(const float4*)(Wl + (k + 3) * 64 + 4 * tc);
#pragma unroll
        for (int r = 0; r < 4; ++r) {
            const float4 A = *(const float4*)(xs + XSW(4 * tr + r, k));
            fma4(acc[r], A.x, B0); fma4(acc[r], A.y, B1);
            fma4(acc[r], A.z, B2); fma4(acc[r], A.w, B3);
        }
    }

    const float4 asv = *(const float4*)(a_s2 + 4 * tc);
    const float4 adv = *(const float4*)(a_d2 + 4 * tc);
#pragma unroll
    for (int r = 0; r < 4; ++r) {
        const int row = row0 + 4 * tr + r;
        if (row < NN) {
            ushort4 pk;
            pk.x = (u16)bf16rne(acc[r][0]); pk.y = (u16)bf16rne(acc[r][1]);
            pk.z = (u16)bf16rne(acc[r][2]); pk.w = (u16)bf16rne(acc[r][3]);
            *(ushort4*)(h2s + row * 64 + 4 * tc) = pk;
            float ps = acc[r][0] * asv.x + acc[r][1] * asv.y +
                       acc[r][2] * asv.z + acc[r][3] * asv.w;
            float pd = acc[r][0] * adv.x + acc[r][1] * adv.y +
                       acc[r][2] * adv.z + acc[r][3] * adv.w;
            ps += __shfl_xor(ps, 1); ps += __shfl_xor(ps, 2);
            ps += __shfl_xor(ps, 4); ps += __shfl_xor(ps, 8);
            pd += __shfl_xor(pd, 1); pd += __shfl_xor(pd, 2);
            pd += __shfl_xor(pd, 4); pd += __shfl_xor(pd, 8);
            if (tc == 0) { as2[row] = ps; ad2[row] = pd; }
        }
    }
}

// ---------------------------------------------------------------------------
// Aggregation layer 1, CSR gather: one node per wave, lane covers channels
// 2*lane, 2*lane+1 via one packed-bf16 dword (head = lane>>3). Unroll-4 for
// MLP. Per-edge exp is 8x-redundant across head lanes but VALU-cheap vs the
// LDS-pipe shuffle alternative (round-6 regression). Fuses /den + ELU.
// ---------------------------------------------------------------------------
__global__ __launch_bounds__(256) void k_agg1(
    const int* __restrict__ rowptr, const int* __restrict__ rowend,
    const int* __restrict__ sorted_src,
    const u32* __restrict__ h1b, const float* __restrict__ as1,
    const float* __restrict__ ad1,
    float* __restrict__ act2)
{
    const int node = blockIdx.x * 4 + (threadIdx.x >> 6);
    const int lane = threadIdx.x & 63;
    const int head = lane >> 3;
    const float adh = ad1[node * NH + head];
    const int k0 = rowptr[node], k1 = rowend[node];
    float acc0 = 0.f, acc1 = 0.f, den = 0.f;
    int k = k0;
    for (; k + 4 <= k1; k += 4) {
        const int s0 = sorted_src[k],     s1 = sorted_src[k + 1];
        const int s2 = sorted_src[k + 2], s3 = sorted_src[k + 3];
        const u32 u0 = h1b[s0 * 64 + lane];
        const u32 u1 = h1b[s1 * 64 + lane];
        const u32 u2 = h1b[s2 * 64 + lane];
        const u32 u3 = h1b[s3 * 64 + lane];
        const float a0 = as1[s0 * NH + head], a1 = as1[s1 * NH + head];
        const float a2 = as1[s2 * NH + head], a3 = as1[s3 * NH + head];
        const float w0 = __expf(LR(a0 + adh)), w1 = __expf(LR(a1 + adh));
        const float w2 = __expf(LR(a2 + adh)), w3 = __expf(LR(a3 + adh));
        acc0 += w0 * __uint_as_float(u0 << 16);
        acc1 += w0 * __uint_as_float(u0 & 0xffff0000u);
        acc0 += w1 * __uint_as_float(u1 << 16);
        acc1 += w1 * __uint_as_float(u1 & 0xffff0000u);
        acc0 += w2 * __uint_as_float(u2 << 16);
        acc1 += w2 * __uint_as_float(u2 & 0xffff0000u);
        acc0 += w3 * __uint_as_float(u3 << 16);
        acc1 += w3 * __uint_as_float(u3 & 0xffff0000u);
        den  += (w0 + w1) + (w2 + w3);
    }
    for (; k < k1; ++k) {
        const int src = sorted_src[k];
        const float w = __expf(LR(as1[src * NH + head] + adh));
        const u32 u = h1b[src * 64 + lane];
        acc0 += w * __uint_as_float(u << 16);
        acc1 += w * __uint_as_float(u & 0xffff0000u);
        den += w;
    }
    const float inv = 1.f / den;                    // self-loop => den > 0
    float v0 = acc0 * inv, v1 = acc1 * inv;
    v0 = v0 > 0.f ? v0 : expm1f(v0);                // ELU
    v1 = v1 > 0.f ? v1 : expm1f(v1);
    *(float2*)(act2 + node * 128 + 2 * lane) = make_float2(v0, v1);
}

// ---------------------------------------------------------------------------
// Layer-2 edge weights, node-parallel (dst implicit = node, no sorted_dst):
// one wave per node, lanes stride the CSR row. Sequential reads of
// sorted_src, random 4B as2 gathers, sequential wbuf2 writes.
// ---------------------------------------------------------------------------
__global__ __launch_bounds__(256) void k_ew2n(
    const int* __restrict__ rowptr, const int* __restrict__ rowend,
    const int* __restrict__ sorted_src,
    const float* __restrict__ as2, const float* __restrict__ ad2,
    float* __restrict__ wbuf2)
{
    const int node = blockIdx.x * 4 + (threadIdx.x >> 6);
    const int lane = threadIdx.x & 63;
    const float adv = ad2[node];
    const int k1 = rowend[node];
    for (int k = rowptr[node] + lane; k < k1; k += 64)
        wbuf2[k] = __expf(LR(as2[sorted_src[k]] + adv));
}

// ---------------------------------------------------------------------------
// Aggregation layer 2 + log_softmax: one node per wave, lane = channel (64),
// bf16 h2 gather + precomputed weights (k wave-uniform -> scalar loads).
// Unroll-4. Fuses normalize + log_softmax -> output.
// ---------------------------------------------------------------------------
__global__ __launch_bounds__(256) void k_agg2(
    const int* __restrict__ rowptr, const int* __restrict__ rowend,
    const int* __restrict__ sorted_src, const float* __restrict__ wbuf2,
    const u16* __restrict__ h2s,
    float* __restrict__ out)
{
    const int node = blockIdx.x * 4 + (threadIdx.x >> 6);
    const int lane = threadIdx.x & 63;
    const int k0 = rowptr[node], k1 = rowend[node];
    float acc = 0.f, den = 0.f;
    int k = k0;
    for (; k + 4 <= k1; k += 4) {
        const int s0 = sorted_src[k],     s1 = sorted_src[k + 1];
        const int s2 = sorted_src[k + 2], s3 = sorted_src[k + 3];
        const float w0 = wbuf2[k],     w1 = wbuf2[k + 1];
        const float w2 = wbuf2[k + 2], w3 = wbuf2[k + 3];
        const u32 u0 = h2s[s0 * 64 + lane];
        const u32 u1 = h2s[s1 * 64 + lane];
        const u32 u2 = h2s[s2 * 64 + lane];
        const u32 u3 = h2s[s3 * 64 + lane];
        acc += w0 * __uint_as_float(u0 << 16);
        acc += w1 * __uint_as_float(u1 << 16);
        acc += w2 * __uint_as_float(u2 << 16);
        acc += w3 * __uint_as_float(u3 << 16);
        den += (w0 + w1) + (w2 + w3);
    }
    for (; k < k1; ++k) {
        const float w = wbuf2[k];
        acc += w * __uint_as_float((u32)h2s[sorted_src[k] * 64 + lane] << 16);
        den += w;
    }
    const float v = acc / den;
    float m = v;
    for (int kk = 1; kk < 64; kk <<= 1) m = fmaxf(m, __shfl_xor(m, kk));
    float se = __expf(v - m);
    for (int kk = 1; kk < 64; kk <<= 1) se += __shfl_xor(se, kk);
    out[node * 64 + lane] = v - m - logf(se);
}

// ---------------------------------------------------------------------------
// Workspace (~48.9 MB, 4-byte units):
//   h1b    [64N] u32 (bf16x2) -> after agg1, reused as h2s [64N] u16
//   as1    [8N]  f32 -> reused as as2 [N]
//   ad1    [8N]  f32 -> reused as ad2 [N]
//   act2   [128N] f32
//   rowptr [N], cursor [N] (deg -> start cursor -> rowend)
//   sorted_src [ET], wbuf2 [ET] f32, partial [256]
// ---------------------------------------------------------------------------
extern "C" void kernel_launch(void* const* d_in, const int* in_sizes, int n_in,
                              void* d_out, int out_size, void* d_ws, size_t ws_size,
                              hipStream_t stream)
{
    (void)in_sizes; (void)n_in; (void)out_size; (void)ws_size;
    const float* x    = (const float*)d_in[0];
    const int*   ei   = (const int*)d_in[1];
    const float* W1   = (const float*)d_in[2];
    const float* as1w = (const float*)d_in[3];
    const float* ad1w = (const float*)d_in[4];
    const float* W2   = (const float*)d_in[6];
    const float* as2w = (const float*)d_in[7];
    const float* ad2w = (const float*)d_in[8];
    float* out = (float*)d_out;

    float* ws = (float*)d_ws;
    u32*   h1b  = (u32*)ws;                          // 64N
    float* as1  = ws + (size_t)64 * NN;              // 8N
    float* ad1  = ws + (size_t)72 * NN;              // 8N
    float* act2 = ws + (size_t)80 * NN;              // 128N
    int*   rowptr = (int*)(ws + (size_t)208 * NN);   // N
    int*   cursor = rowptr + NN;                     // N
    int*   sorted_src = cursor + NN;                 // ET
    float* wbuf2 = (float*)(sorted_src + ET);        // ET
    int*   partial = (int*)(wbuf2 + ET);             // 256
    u16*   h2s = (u16*)h1b;                          // alias (h1b dead after agg1)
    float* as2 = as1;
    float* ad2 = ad1;

    hipMemsetAsync(cursor, 0, NN * sizeof(int), stream);

    const int EB = (ET + 255) / 256;
    k_deg  <<<EB, 256, 0, stream>>>(ei, cursor);
    k_scanA<<<NBLK, 256, 0, stream>>>(cursor, partial);
    k_scanB<<<1, 256, 0, stream>>>(partial);
    k_scanC<<<NBLK, 256, 0, stream>>>(cursor, partial, rowptr);
    k_scatter<<<EB, 256, 0, stream>>>(ei, cursor, sorted_src);

    k_gemm1<<<dim3(782, 2), 256, 0, stream>>>(x, W1, as1w, ad1w, h1b, as1, ad1);
    k_agg1 <<<NN / 4, 256, 0, stream>>>(rowptr, cursor, sorted_src, h1b, as1, ad1, act2);
    k_gemm2<<<dim3(782, 1), 256, 0, stream>>>(act2, W2, as2w, ad2w, h2s, as2, ad2);
    k_ew2n <<<NN / 4, 256, 0, stream>>>(rowptr, cursor, sorted_src, as2, ad2, wbuf2);
    k_agg2 <<<NN / 4, 256, 0, stream>>>(rowptr, cursor, sorted_src, wbuf2, h2s, out);
}